// Round 1
// baseline (888.952 us; speedup 1.0000x reference)
//
#include <hip/hip_runtime.h>

#define BSZ 256
#define NND 22
#define BN_EPS 1e-5f

// ---------------------------------------------------------------------------
// Pass 1 per block: conv1d(k=7,pad=3) + accumulate per-(node,channel) sum/sum^2
// grid: (ceil(LIN/256), B, N), block: 256
// ---------------------------------------------------------------------------
template<int CIN, int COUT, int LIN>
__global__ __launch_bounds__(256) void conv_stats(
    const float* __restrict__ in, long sn, long sb, long sc,
    const float* __restrict__ w,
    float* __restrict__ gsum, float* __restrict__ gsumsq) {
  __shared__ float s_in[CIN][256 + 8];
  __shared__ float s_part[2][4][COUT];
  int tid = threadIdx.x;
  int n = blockIdx.z, b = blockIdx.y;
  int t0 = blockIdx.x * 256;
  const float* base = in + (long)n * sn + (long)b * sb;
  for (int c = 0; c < CIN; c++)
    for (int i = tid; i < 256 + 6; i += 256) {
      int l = t0 + i - 3;
      s_in[c][i] = (l >= 0 && l < LIN) ? base[(long)c * sc + l] : 0.f;
    }
  __syncthreads();
  int l = t0 + tid;
  bool valid = (l < LIN);
  float acc[COUT];
#pragma unroll
  for (int o = 0; o < COUT; o++) acc[o] = 0.f;
#pragma unroll
  for (int c = 0; c < CIN; c++) {
#pragma unroll
    for (int k = 0; k < 7; k++) {
      float xv = s_in[c][tid + k];
#pragma unroll
      for (int o = 0; o < COUT; o++)
        acc[o] += xv * w[(o * CIN + c) * 7 + k];  // uniform -> s_load
    }
  }
  int wv = tid >> 6, lane = tid & 63;
#pragma unroll
  for (int o = 0; o < COUT; o++) {
    float v = valid ? acc[o] : 0.f;
    float v2 = v * v;
#pragma unroll
    for (int off = 32; off > 0; off >>= 1) {
      v += __shfl_down(v, off, 64);
      v2 += __shfl_down(v2, off, 64);
    }
    if (lane == 0) { s_part[0][wv][o] = v; s_part[1][wv][o] = v2; }
  }
  __syncthreads();
  if (tid < COUT) {
    float s = s_part[0][0][tid] + s_part[0][1][tid] + s_part[0][2][tid] + s_part[0][3][tid];
    float s2 = s_part[1][0][tid] + s_part[1][1][tid] + s_part[1][2][tid] + s_part[1][3][tid];
    atomicAdd(&gsum[n * COUT + tid], s);
    atomicAdd(&gsumsq[n * COUT + tid], s2);
  }
}

// ---------------------------------------------------------------------------
// Pass 2 per block: conv again + BN(train stats) + ReLU + MaxPool(2) -> h
// grid: (ceil(LP/256), B, N), block: 256.  outh layout [n][b][COUT][LP]
// ---------------------------------------------------------------------------
template<int CIN, int COUT, int LIN>
__global__ __launch_bounds__(256) void conv_bn_pool(
    const float* __restrict__ in, long sn, long sb, long sc,
    const float* __restrict__ w,
    const float* __restrict__ gamma, const float* __restrict__ beta,
    const float* __restrict__ gsum, const float* __restrict__ gsumsq,
    float* __restrict__ outh) {
  const int LP = LIN / 2;
  __shared__ float s_in[CIN][2 * 256 + 8];
  __shared__ float s_scale[COUT], s_shift[COUT];
  int tid = threadIdx.x;
  int n = blockIdx.z, b = blockIdx.y;
  int p0 = blockIdx.x * 256;
  const float* base = in + (long)n * sn + (long)b * sb;
  if (tid < COUT) {
    float cnt = (float)BSZ * (float)LIN;
    float m = gsum[n * COUT + tid] / cnt;
    float v = gsumsq[n * COUT + tid] / cnt - m * m;
    float istd = 1.0f / sqrtf(v + BN_EPS);
    float scl = gamma[tid] * istd;
    s_scale[tid] = scl;
    s_shift[tid] = beta[tid] - m * scl;
  }
  int l0 = 2 * p0 - 3;
  for (int c = 0; c < CIN; c++)
    for (int i = tid; i < 2 * 256 + 7; i += 256) {
      int l = l0 + i;
      s_in[c][i] = (l >= 0 && l < LIN) ? base[(long)c * sc + l] : 0.f;
    }
  __syncthreads();
  int pl = p0 + tid;
  if (pl >= LP) return;
  float a0[COUT], a1[COUT];
#pragma unroll
  for (int o = 0; o < COUT; o++) { a0[o] = 0.f; a1[o] = 0.f; }
#pragma unroll
  for (int c = 0; c < CIN; c++) {
#pragma unroll
    for (int k = 0; k < 7; k++) {
      float x0 = s_in[c][2 * tid + k];
      float x1 = s_in[c][2 * tid + 1 + k];
#pragma unroll
      for (int o = 0; o < COUT; o++) {
        float wv = w[(o * CIN + c) * 7 + k];
        a0[o] += x0 * wv;
        a1[o] += x1 * wv;
      }
    }
  }
  long obase = ((long)n * BSZ + b) * COUT * (long)LP + pl;
#pragma unroll
  for (int o = 0; o < COUT; o++) {
    float r0 = a0[o] * s_scale[o] + s_shift[o];
    float r1 = a1[o] * s_scale[o] + s_shift[o];
    outh[obase + (long)o * LP] = fmaxf(fmaxf(r0, r1), 0.f);
  }
}

// ---------------------------------------------------------------------------
// Block 3 pass 2 fused with AdaptiveAvgPool(1): writes feat[b][n][16] directly.
// grid: (1, B, N), block 256 (covers whole LP=250 row)
// ---------------------------------------------------------------------------
template<int CIN, int COUT, int LIN>
__global__ __launch_bounds__(256) void conv_bn_pool_feat(
    const float* __restrict__ in, long sn, long sb, long sc,
    const float* __restrict__ w,
    const float* __restrict__ gamma, const float* __restrict__ beta,
    const float* __restrict__ gsum, const float* __restrict__ gsumsq,
    float* __restrict__ feat) {
  const int LP = LIN / 2;
  __shared__ float s_in[CIN][2 * 256 + 8];
  __shared__ float s_scale[COUT], s_shift[COUT];
  __shared__ float s_part[4][COUT];
  int tid = threadIdx.x;
  int n = blockIdx.z, b = blockIdx.y;
  const float* base = in + (long)n * sn + (long)b * sb;
  if (tid < COUT) {
    float cnt = (float)BSZ * (float)LIN;
    float m = gsum[n * COUT + tid] / cnt;
    float v = gsumsq[n * COUT + tid] / cnt - m * m;
    float istd = 1.0f / sqrtf(v + BN_EPS);
    float scl = gamma[tid] * istd;
    s_scale[tid] = scl;
    s_shift[tid] = beta[tid] - m * scl;
  }
  for (int c = 0; c < CIN; c++)
    for (int i = tid; i < 2 * 256 + 7; i += 256) {
      int l = i - 3;
      s_in[c][i] = (l >= 0 && l < LIN) ? base[(long)c * sc + l] : 0.f;
    }
  __syncthreads();
  bool valid = (tid < LP);
  float a0[COUT], a1[COUT];
#pragma unroll
  for (int o = 0; o < COUT; o++) { a0[o] = 0.f; a1[o] = 0.f; }
#pragma unroll
  for (int c = 0; c < CIN; c++) {
#pragma unroll
    for (int k = 0; k < 7; k++) {
      float x0 = s_in[c][2 * tid + k];
      float x1 = s_in[c][2 * tid + 1 + k];
#pragma unroll
      for (int o = 0; o < COUT; o++) {
        float wv = w[(o * CIN + c) * 7 + k];
        a0[o] += x0 * wv;
        a1[o] += x1 * wv;
      }
    }
  }
  int wv2 = tid >> 6, lane = tid & 63;
#pragma unroll
  for (int o = 0; o < COUT; o++) {
    float r0 = a0[o] * s_scale[o] + s_shift[o];
    float r1 = a1[o] * s_scale[o] + s_shift[o];
    float h = valid ? fmaxf(fmaxf(r0, r1), 0.f) : 0.f;
#pragma unroll
    for (int off = 32; off > 0; off >>= 1) h += __shfl_down(h, off, 64);
    if (lane == 0) s_part[wv2][o] = h;
  }
  __syncthreads();
  if (tid < COUT) {
    float s = s_part[0][tid] + s_part[1][tid] + s_part[2][tid] + s_part[3][tid];
    feat[((long)b * NND + n) * COUT + tid] = s * (1.0f / (float)LP);
  }
}

// ---------------------------------------------------------------------------
// Graph tail: adjacency (top-4 incl self) + 3 GCN layers + node-mean + MLP head
// grid: (B), block: 256. One workgroup per batch element, all in LDS.
// ---------------------------------------------------------------------------
__global__ __launch_bounds__(256) void graph_head(
    const float* __restrict__ feat,
    const float* __restrict__ gw1, const float* __restrict__ gb1,
    const float* __restrict__ gw2, const float* __restrict__ gb2,
    const float* __restrict__ gw3, const float* __restrict__ gb3,
    const float* __restrict__ fw1, const float* __restrict__ fb1,
    const float* __restrict__ fw2, const float* __restrict__ fb2,
    float* __restrict__ out) {
  int b = blockIdx.x, tid = threadIdx.x;
  __shared__ float s_feat[NND][16];
  __shared__ float s_sq[NND];
  __shared__ float s_dist[NND][NND];
  __shared__ float s_adj[NND][NND];
  __shared__ float s_x[NND][128];
  __shared__ float s_t[NND][128];
  __shared__ float s_pool[128];
  __shared__ float s_h[64];
  for (int i = tid; i < NND * 16; i += 256) s_feat[i >> 4][i & 15] = feat[b * NND * 16 + i];
  __syncthreads();
  if (tid < NND) {
    float s = 0.f;
    for (int c = 0; c < 16; c++) s += s_feat[tid][c] * s_feat[tid][c];
    s_sq[tid] = s;
  }
  __syncthreads();
  for (int i = tid; i < NND * NND; i += 256) {
    int nn = i / NND, m = i % NND;
    float d = 0.f;
    for (int c = 0; c < 16; c++) d += s_feat[nn][c] * s_feat[m][c];
    s_dist[nn][m] = s_sq[nn] + s_sq[m] - 2.f * d;  // diagonal exactly 0
    s_adj[nn][m] = 0.f;
  }
  __syncthreads();
  if (tid < NND) {  // top-4 smallest per row, ties -> earliest index (matches top_k)
    unsigned used = 0;
    for (int j = 0; j < 4; j++) {
      float best = 3.4e38f; int bi = 0;
      for (int m = 0; m < NND; m++)
        if (!((used >> m) & 1u) && s_dist[tid][m] < best) { best = s_dist[tid][m]; bi = m; }
      used |= 1u << bi;
      s_adj[tid][bi] = 0.25f;
    }
  }
  __syncthreads();
  // ---- GCN layer 1: 16 -> 32 ----
  for (int i = tid; i < NND * 32; i += 256) {
    int nn = i / 32, f = i % 32;
    float a = 0.f;
    for (int c = 0; c < 16; c++) a += s_feat[nn][c] * gw1[c * 32 + f];
    s_t[nn][f] = a;
  }
  __syncthreads();
  for (int i = tid; i < NND * 32; i += 256) {
    int nn = i / 32, f = i % 32;
    float a = gb1[f];
    for (int m = 0; m < NND; m++) a += s_adj[nn][m] * s_t[m][f];
    s_x[nn][f] = fmaxf(a, 0.f);
  }
  __syncthreads();
  // ---- GCN layer 2: 32 -> 64 ----
  for (int i = tid; i < NND * 64; i += 256) {
    int nn = i / 64, f = i % 64;
    float a = 0.f;
    for (int c = 0; c < 32; c++) a += s_x[nn][c] * gw2[c * 64 + f];
    s_t[nn][f] = a;
  }
  __syncthreads();
  for (int i = tid; i < NND * 64; i += 256) {
    int nn = i / 64, f = i % 64;
    float a = gb2[f];
    for (int m = 0; m < NND; m++) a += s_adj[nn][m] * s_t[m][f];
    s_x[nn][f] = fmaxf(a, 0.f);
  }
  __syncthreads();
  // ---- GCN layer 3: 64 -> 128 ----
  for (int i = tid; i < NND * 128; i += 256) {
    int nn = i / 128, f = i % 128;
    float a = 0.f;
    for (int c = 0; c < 64; c++) a += s_x[nn][c] * gw3[c * 128 + f];
    s_t[nn][f] = a;
  }
  __syncthreads();
  for (int i = tid; i < NND * 128; i += 256) {
    int nn = i / 128, f = i % 128;
    float a = gb3[f];
    for (int m = 0; m < NND; m++) a += s_adj[nn][m] * s_t[m][f];
    s_x[nn][f] = fmaxf(a, 0.f);
  }
  __syncthreads();
  if (tid < 128) {
    float a = 0.f;
    for (int m = 0; m < NND; m++) a += s_x[m][tid];
    s_pool[tid] = a * (1.0f / (float)NND);
  }
  __syncthreads();
  if (tid < 64) {
    float a = fb1[tid];
    for (int c = 0; c < 128; c++) a += s_pool[c] * fw1[c * 64 + tid];
    s_h[tid] = a;
  }
  __syncthreads();
  if (tid < 4) {
    float a = fb2[tid];
    for (int c = 0; c < 64; c++) a += s_h[c] * fw2[c * 4 + tid];
    out[b * 4 + tid] = a;
  }
}

extern "C" void kernel_launch(void* const* d_in, const int* in_sizes, int n_in,
                              void* d_out, int out_size, void* d_ws, size_t ws_size,
                              hipStream_t stream) {
  (void)in_sizes; (void)n_in; (void)out_size; (void)ws_size;
  const float* x   = (const float*)d_in[0];
  const float* w1  = (const float*)d_in[1];
  const float* g1  = (const float*)d_in[2];
  const float* b1  = (const float*)d_in[3];
  const float* w2  = (const float*)d_in[4];
  const float* g2  = (const float*)d_in[5];
  const float* b2  = (const float*)d_in[6];
  const float* w3  = (const float*)d_in[7];
  const float* g3  = (const float*)d_in[8];
  const float* b3  = (const float*)d_in[9];
  const float* gw1 = (const float*)d_in[10];
  const float* gb1 = (const float*)d_in[11];
  const float* gw2 = (const float*)d_in[12];
  const float* gb2 = (const float*)d_in[13];
  const float* gw3 = (const float*)d_in[14];
  const float* gb3 = (const float*)d_in[15];
  const float* fw1 = (const float*)d_in[16];
  const float* fb1 = (const float*)d_in[17];
  const float* fw2 = (const float*)d_in[18];
  const float* fb2 = (const float*)d_in[19];

  float* ws = (float*)d_ws;
  const long H1 = (long)NND * BSZ * 4 * 1000;  // 22,528,000 floats
  const long H2 = (long)NND * BSZ * 8 * 500;   // 22,528,000 floats
  float* h1   = ws;
  float* h2   = h1 + H1;
  float* feat = h2 + H2;                        // B*N*16 = 90,112
  float* st   = feat + (long)BSZ * NND * 16;    // stats: 1232 floats
  float* s1 = st;        float* q1 = s1 + 88;
  float* s2 = q1 + 88;   float* q2 = s2 + 176;
  float* s3 = q2 + 176;  float* q3 = s3 + 352;
  // total ws: ~180.7 MB

  hipMemsetAsync(st, 0, 1232 * sizeof(float), stream);

  dim3 blk(256);
  // block 1: input x is (B, N, T): node stride T, batch stride N*T
  conv_stats<1, 4, 2000><<<dim3(8, BSZ, NND), blk, 0, stream>>>(
      x, 2000, (long)NND * 2000, 0, w1, s1, q1);
  conv_bn_pool<1, 4, 2000><<<dim3(4, BSZ, NND), blk, 0, stream>>>(
      x, 2000, (long)NND * 2000, 0, w1, g1, b1, s1, q1, h1);
  // block 2: h1 layout [n][b][4][1000]
  conv_stats<4, 8, 1000><<<dim3(4, BSZ, NND), blk, 0, stream>>>(
      h1, (long)BSZ * 4000, 4000, 1000, w2, s2, q2);
  conv_bn_pool<4, 8, 1000><<<dim3(2, BSZ, NND), blk, 0, stream>>>(
      h1, (long)BSZ * 4000, 4000, 1000, w2, g2, b2, s2, q2, h2);
  // block 3: h2 layout [n][b][8][500]; apply pass fused with avg-pool -> feat
  conv_stats<8, 16, 500><<<dim3(2, BSZ, NND), blk, 0, stream>>>(
      h2, (long)BSZ * 4000, 4000, 500, w3, s3, q3);
  conv_bn_pool_feat<8, 16, 500><<<dim3(1, BSZ, NND), blk, 0, stream>>>(
      h2, (long)BSZ * 4000, 4000, 500, w3, g3, b3, s3, q3, feat);
  // graph tail
  graph_head<<<dim3(BSZ), blk, 0, stream>>>(
      feat, gw1, gb1, gw2, gb2, gw3, gb3, fw1, fb1, fw2, fb2, (float*)d_out);
}

// Round 2
// 565.103 us; speedup vs baseline: 1.5731x; 1.5731x over previous
//
#include <hip/hip_runtime.h>

#define BSZ 256
#define NND 22
#define BN_EPS 1e-5f

// ---------------------------------------------------------------------------
// Stats pass: conv1d(k=7,pad=3) + per-(node,channel) sum/sum^2.
// One block covers BCH full batch rows (loops over length tiles internally,
// accumulates in registers, single atomic per channel at the end).
// grid: (B/BCH, 1, N), block: 256
// ---------------------------------------------------------------------------
template<int CIN, int COUT, int LIN, int BCH>
__global__ __launch_bounds__(256) void conv_stats(
    const float* __restrict__ in, long sn, long sb, long sc,
    const float* __restrict__ w,
    float* __restrict__ gsum, float* __restrict__ gsumsq) {
  __shared__ float s_in[CIN][256 + 8];
  __shared__ float s_part[2][4][COUT];
  int tid = threadIdx.x;
  int n = blockIdx.z;
  int b0 = blockIdx.x * BCH;
  float accS[COUT], accQ[COUT];
#pragma unroll
  for (int o = 0; o < COUT; o++) { accS[o] = 0.f; accQ[o] = 0.f; }

  for (int bb = 0; bb < BCH; bb++) {
    const float* base = in + (long)n * sn + (long)(b0 + bb) * sb;
    for (int t0 = 0; t0 < LIN; t0 += 256) {
      for (int c = 0; c < CIN; c++)
        for (int i = tid; i < 256 + 6; i += 256) {
          int l = t0 + i - 3;
          s_in[c][i] = (l >= 0 && l < LIN) ? base[(long)c * sc + l] : 0.f;
        }
      __syncthreads();
      int l = t0 + tid;
      if (l < LIN) {
        float acc[COUT];
#pragma unroll
        for (int o = 0; o < COUT; o++) acc[o] = 0.f;
#pragma unroll
        for (int c = 0; c < CIN; c++) {
#pragma unroll
          for (int k = 0; k < 7; k++) {
            float xv = s_in[c][tid + k];
#pragma unroll
            for (int o = 0; o < COUT; o++)
              acc[o] += xv * w[(o * CIN + c) * 7 + k];  // uniform -> s_load
          }
        }
#pragma unroll
        for (int o = 0; o < COUT; o++) {
          accS[o] += acc[o];
          accQ[o] += acc[o] * acc[o];
        }
      }
      __syncthreads();
    }
  }

  int wv = tid >> 6, lane = tid & 63;
#pragma unroll
  for (int o = 0; o < COUT; o++) {
    float v = accS[o], v2 = accQ[o];
#pragma unroll
    for (int off = 32; off > 0; off >>= 1) {
      v += __shfl_down(v, off, 64);
      v2 += __shfl_down(v2, off, 64);
    }
    if (lane == 0) { s_part[0][wv][o] = v; s_part[1][wv][o] = v2; }
  }
  __syncthreads();
  if (tid < COUT) {
    float s = s_part[0][0][tid] + s_part[0][1][tid] + s_part[0][2][tid] + s_part[0][3][tid];
    float s2 = s_part[1][0][tid] + s_part[1][1][tid] + s_part[1][2][tid] + s_part[1][3][tid];
    atomicAdd(&gsum[n * COUT + tid], s);
    atomicAdd(&gsumsq[n * COUT + tid], s2);
  }
}

// ---------------------------------------------------------------------------
// Apply pass: conv again + BN(train stats) + ReLU + MaxPool(2) -> h
// grid: (ceil(LP/256), B, N), block: 256.  outh layout [n][b][COUT][LP]
// ---------------------------------------------------------------------------
template<int CIN, int COUT, int LIN>
__global__ __launch_bounds__(256) void conv_bn_pool(
    const float* __restrict__ in, long sn, long sb, long sc,
    const float* __restrict__ w,
    const float* __restrict__ gamma, const float* __restrict__ beta,
    const float* __restrict__ gsum, const float* __restrict__ gsumsq,
    float* __restrict__ outh) {
  const int LP = LIN / 2;
  __shared__ float s_in[CIN][2 * 256 + 8];
  __shared__ float s_scale[COUT], s_shift[COUT];
  int tid = threadIdx.x;
  int n = blockIdx.z, b = blockIdx.y;
  int p0 = blockIdx.x * 256;
  const float* base = in + (long)n * sn + (long)b * sb;
  if (tid < COUT) {
    float cnt = (float)BSZ * (float)LIN;
    float m = gsum[n * COUT + tid] / cnt;
    float v = gsumsq[n * COUT + tid] / cnt - m * m;
    float istd = 1.0f / sqrtf(v + BN_EPS);
    float scl = gamma[tid] * istd;
    s_scale[tid] = scl;
    s_shift[tid] = beta[tid] - m * scl;
  }
  int l0 = 2 * p0 - 3;
  for (int c = 0; c < CIN; c++)
    for (int i = tid; i < 2 * 256 + 7; i += 256) {
      int l = l0 + i;
      s_in[c][i] = (l >= 0 && l < LIN) ? base[(long)c * sc + l] : 0.f;
    }
  __syncthreads();
  int pl = p0 + tid;
  if (pl >= LP) return;
  float a0[COUT], a1[COUT];
#pragma unroll
  for (int o = 0; o < COUT; o++) { a0[o] = 0.f; a1[o] = 0.f; }
#pragma unroll
  for (int c = 0; c < CIN; c++) {
#pragma unroll
    for (int k = 0; k < 7; k++) {
      float x0 = s_in[c][2 * tid + k];
      float x1 = s_in[c][2 * tid + 1 + k];
#pragma unroll
      for (int o = 0; o < COUT; o++) {
        float wv = w[(o * CIN + c) * 7 + k];
        a0[o] += x0 * wv;
        a1[o] += x1 * wv;
      }
    }
  }
  long obase = ((long)n * BSZ + b) * COUT * (long)LP + pl;
#pragma unroll
  for (int o = 0; o < COUT; o++) {
    float r0 = a0[o] * s_scale[o] + s_shift[o];
    float r1 = a1[o] * s_scale[o] + s_shift[o];
    outh[obase + (long)o * LP] = fmaxf(fmaxf(r0, r1), 0.f);
  }
}

// ---------------------------------------------------------------------------
// Block 3 apply fused with AdaptiveAvgPool(1): writes feat[b][n][16] directly.
// grid: (1, B, N), block 256 (covers whole LP=250 row)
// ---------------------------------------------------------------------------
template<int CIN, int COUT, int LIN>
__global__ __launch_bounds__(256) void conv_bn_pool_feat(
    const float* __restrict__ in, long sn, long sb, long sc,
    const float* __restrict__ w,
    const float* __restrict__ gamma, const float* __restrict__ beta,
    const float* __restrict__ gsum, const float* __restrict__ gsumsq,
    float* __restrict__ feat) {
  const int LP = LIN / 2;
  __shared__ float s_in[CIN][2 * 256 + 8];
  __shared__ float s_scale[COUT], s_shift[COUT];
  __shared__ float s_part[4][COUT];
  int tid = threadIdx.x;
  int n = blockIdx.z, b = blockIdx.y;
  const float* base = in + (long)n * sn + (long)b * sb;
  if (tid < COUT) {
    float cnt = (float)BSZ * (float)LIN;
    float m = gsum[n * COUT + tid] / cnt;
    float v = gsumsq[n * COUT + tid] / cnt - m * m;
    float istd = 1.0f / sqrtf(v + BN_EPS);
    float scl = gamma[tid] * istd;
    s_scale[tid] = scl;
    s_shift[tid] = beta[tid] - m * scl;
  }
  for (int c = 0; c < CIN; c++)
    for (int i = tid; i < 2 * 256 + 7; i += 256) {
      int l = i - 3;
      s_in[c][i] = (l >= 0 && l < LIN) ? base[(long)c * sc + l] : 0.f;
    }
  __syncthreads();
  bool valid = (tid < LP);
  float a0[COUT], a1[COUT];
#pragma unroll
  for (int o = 0; o < COUT; o++) { a0[o] = 0.f; a1[o] = 0.f; }
#pragma unroll
  for (int c = 0; c < CIN; c++) {
#pragma unroll
    for (int k = 0; k < 7; k++) {
      float x0 = s_in[c][2 * tid + k];
      float x1 = s_in[c][2 * tid + 1 + k];
#pragma unroll
      for (int o = 0; o < COUT; o++) {
        float wv = w[(o * CIN + c) * 7 + k];
        a0[o] += x0 * wv;
        a1[o] += x1 * wv;
      }
    }
  }
  int wv2 = tid >> 6, lane = tid & 63;
#pragma unroll
  for (int o = 0; o < COUT; o++) {
    float r0 = a0[o] * s_scale[o] + s_shift[o];
    float r1 = a1[o] * s_scale[o] + s_shift[o];
    float h = valid ? fmaxf(fmaxf(r0, r1), 0.f) : 0.f;
#pragma unroll
    for (int off = 32; off > 0; off >>= 1) h += __shfl_down(h, off, 64);
    if (lane == 0) s_part[wv2][o] = h;
  }
  __syncthreads();
  if (tid < COUT) {
    float s = s_part[0][tid] + s_part[1][tid] + s_part[2][tid] + s_part[3][tid];
    feat[((long)b * NND + n) * COUT + tid] = s * (1.0f / (float)LP);
  }
}

// ---------------------------------------------------------------------------
// Graph tail: adjacency (top-4 incl self) + 3 GCN layers + node-mean + MLP head
// grid: (B), block: 256. One workgroup per batch element, all in LDS.
// ---------------------------------------------------------------------------
__global__ __launch_bounds__(256) void graph_head(
    const float* __restrict__ feat,
    const float* __restrict__ gw1, const float* __restrict__ gb1,
    const float* __restrict__ gw2, const float* __restrict__ gb2,
    const float* __restrict__ gw3, const float* __restrict__ gb3,
    const float* __restrict__ fw1, const float* __restrict__ fb1,
    const float* __restrict__ fw2, const float* __restrict__ fb2,
    float* __restrict__ out) {
  int b = blockIdx.x, tid = threadIdx.x;
  __shared__ float s_feat[NND][16];
  __shared__ float s_sq[NND];
  __shared__ float s_dist[NND][NND];
  __shared__ float s_adj[NND][NND];
  __shared__ float s_x[NND][128];
  __shared__ float s_t[NND][128];
  __shared__ float s_pool[128];
  __shared__ float s_h[64];
  for (int i = tid; i < NND * 16; i += 256) s_feat[i >> 4][i & 15] = feat[b * NND * 16 + i];
  __syncthreads();
  if (tid < NND) {
    float s = 0.f;
    for (int c = 0; c < 16; c++) s += s_feat[tid][c] * s_feat[tid][c];
    s_sq[tid] = s;
  }
  __syncthreads();
  for (int i = tid; i < NND * NND; i += 256) {
    int nn = i / NND, m = i % NND;
    float d = 0.f;
    for (int c = 0; c < 16; c++) d += s_feat[nn][c] * s_feat[m][c];
    s_dist[nn][m] = s_sq[nn] + s_sq[m] - 2.f * d;  // diagonal exactly 0
    s_adj[nn][m] = 0.f;
  }
  __syncthreads();
  if (tid < NND) {  // top-4 smallest per row, ties -> earliest index (matches top_k)
    unsigned used = 0;
    for (int j = 0; j < 4; j++) {
      float best = 3.4e38f; int bi = 0;
      for (int m = 0; m < NND; m++)
        if (!((used >> m) & 1u) && s_dist[tid][m] < best) { best = s_dist[tid][m]; bi = m; }
      used |= 1u << bi;
      s_adj[tid][bi] = 0.25f;
    }
  }
  __syncthreads();
  // ---- GCN layer 1: 16 -> 32 ----
  for (int i = tid; i < NND * 32; i += 256) {
    int nn = i / 32, f = i % 32;
    float a = 0.f;
    for (int c = 0; c < 16; c++) a += s_feat[nn][c] * gw1[c * 32 + f];
    s_t[nn][f] = a;
  }
  __syncthreads();
  for (int i = tid; i < NND * 32; i += 256) {
    int nn = i / 32, f = i % 32;
    float a = gb1[f];
    for (int m = 0; m < NND; m++) a += s_adj[nn][m] * s_t[m][f];
    s_x[nn][f] = fmaxf(a, 0.f);
  }
  __syncthreads();
  // ---- GCN layer 2: 32 -> 64 ----
  for (int i = tid; i < NND * 64; i += 256) {
    int nn = i / 64, f = i % 64;
    float a = 0.f;
    for (int c = 0; c < 32; c++) a += s_x[nn][c] * gw2[c * 64 + f];
    s_t[nn][f] = a;
  }
  __syncthreads();
  for (int i = tid; i < NND * 64; i += 256) {
    int nn = i / 64, f = i % 64;
    float a = gb2[f];
    for (int m = 0; m < NND; m++) a += s_adj[nn][m] * s_t[m][f];
    s_x[nn][f] = fmaxf(a, 0.f);
  }
  __syncthreads();
  // ---- GCN layer 3: 64 -> 128 ----
  for (int i = tid; i < NND * 128; i += 256) {
    int nn = i / 128, f = i % 128;
    float a = 0.f;
    for (int c = 0; c < 64; c++) a += s_x[nn][c] * gw3[c * 128 + f];
    s_t[nn][f] = a;
  }
  __syncthreads();
  for (int i = tid; i < NND * 128; i += 256) {
    int nn = i / 128, f = i % 128;
    float a = gb3[f];
    for (int m = 0; m < NND; m++) a += s_adj[nn][m] * s_t[m][f];
    s_x[nn][f] = fmaxf(a, 0.f);
  }
  __syncthreads();
  if (tid < 128) {
    float a = 0.f;
    for (int m = 0; m < NND; m++) a += s_x[m][tid];
    s_pool[tid] = a * (1.0f / (float)NND);
  }
  __syncthreads();
  if (tid < 64) {
    float a = fb1[tid];
    for (int c = 0; c < 128; c++) a += s_pool[c] * fw1[c * 64 + tid];
    s_h[tid] = a;
  }
  __syncthreads();
  if (tid < 4) {
    float a = fb2[tid];
    for (int c = 0; c < 64; c++) a += s_h[c] * fw2[c * 4 + tid];
    out[b * 4 + tid] = a;
  }
}

extern "C" void kernel_launch(void* const* d_in, const int* in_sizes, int n_in,
                              void* d_out, int out_size, void* d_ws, size_t ws_size,
                              hipStream_t stream) {
  (void)in_sizes; (void)n_in; (void)out_size; (void)ws_size;
  const float* x   = (const float*)d_in[0];
  const float* w1  = (const float*)d_in[1];
  const float* g1  = (const float*)d_in[2];
  const float* b1  = (const float*)d_in[3];
  const float* w2  = (const float*)d_in[4];
  const float* g2  = (const float*)d_in[5];
  const float* b2  = (const float*)d_in[6];
  const float* w3  = (const float*)d_in[7];
  const float* g3  = (const float*)d_in[8];
  const float* b3  = (const float*)d_in[9];
  const float* gw1 = (const float*)d_in[10];
  const float* gb1 = (const float*)d_in[11];
  const float* gw2 = (const float*)d_in[12];
  const float* gb2 = (const float*)d_in[13];
  const float* gw3 = (const float*)d_in[14];
  const float* gb3 = (const float*)d_in[15];
  const float* fw1 = (const float*)d_in[16];
  const float* fb1 = (const float*)d_in[17];
  const float* fw2 = (const float*)d_in[18];
  const float* fb2 = (const float*)d_in[19];

  float* ws = (float*)d_ws;
  const long H1 = (long)NND * BSZ * 4 * 1000;  // 22,528,000 floats
  const long H2 = (long)NND * BSZ * 8 * 500;   // 22,528,000 floats
  float* h1   = ws;
  float* h2   = h1 + H1;
  float* feat = h2 + H2;                        // B*N*16 = 90,112
  float* st   = feat + (long)BSZ * NND * 16;    // stats: 1232 floats
  float* s1 = st;        float* q1 = s1 + 88;
  float* s2 = q1 + 88;   float* q2 = s2 + 176;
  float* s3 = q2 + 176;  float* q3 = s3 + 352;
  // total ws: ~180.7 MB

  hipMemsetAsync(st, 0, 1232 * sizeof(float), stream);

  dim3 blk(256);
  // block 1: input x is (B, N, T): node stride T, batch stride N*T
  conv_stats<1, 4, 2000, 8><<<dim3(BSZ / 8, 1, NND), blk, 0, stream>>>(
      x, 2000, (long)NND * 2000, 0, w1, s1, q1);
  conv_bn_pool<1, 4, 2000><<<dim3(4, BSZ, NND), blk, 0, stream>>>(
      x, 2000, (long)NND * 2000, 0, w1, g1, b1, s1, q1, h1);
  // block 2: h1 layout [n][b][4][1000]
  conv_stats<4, 8, 1000, 8><<<dim3(BSZ / 8, 1, NND), blk, 0, stream>>>(
      h1, (long)BSZ * 4000, 4000, 1000, w2, s2, q2);
  conv_bn_pool<4, 8, 1000><<<dim3(2, BSZ, NND), blk, 0, stream>>>(
      h1, (long)BSZ * 4000, 4000, 1000, w2, g2, b2, s2, q2, h2);
  // block 3: h2 layout [n][b][8][500]; apply pass fused with avg-pool -> feat
  conv_stats<8, 16, 500, 8><<<dim3(BSZ / 8, 1, NND), blk, 0, stream>>>(
      h2, (long)BSZ * 4000, 4000, 500, w3, s3, q3);
  conv_bn_pool_feat<8, 16, 500><<<dim3(1, BSZ, NND), blk, 0, stream>>>(
      h2, (long)BSZ * 4000, 4000, 500, w3, g3, b3, s3, q3, feat);
  // graph tail
  graph_head<<<dim3(BSZ), blk, 0, stream>>>(
      feat, gw1, gb1, gw2, gb2, gw3, gb3, fw1, fb1, fw2, fb2, (float*)d_out);
}

// Round 3
// 445.559 us; speedup vs baseline: 1.9951x; 1.2683x over previous
//
#include <hip/hip_runtime.h>

#define BSZ 256
#define NND 22
#define BN_EPS 1e-5f

// ---------------------------------------------------------------------------
// Stats pass (flat): conv1d(k=7,pad=3) + per-(node,channel) sum/sum^2.
// One block per (n, b) row. Thread t computes R consecutive conv outputs
// [R*t, R*t+R) fully in registers from aligned float4 loads. No LDS staging,
// no barriers in the hot path. Block reduce + one atomic per channel.
// stats layout per node: stats[n*64 + o] = sum, stats[n*64 + 32 + o] = sumsq
// (sum and sumsq on separate 128B cachelines, nodes padded apart).
// grid: (1, B, N), block: NTH
// ---------------------------------------------------------------------------
template<int CIN, int COUT, int LIN, int R, int NTH>
__global__ __launch_bounds__(NTH) void conv_stats_flat(
    const float* __restrict__ in, long sn, long sb, long sc,
    const float* __restrict__ w,
    float* __restrict__ stats) {
  int tid = threadIdx.x;
  int n = blockIdx.z, b = blockIdx.y;
  float accS[COUT], accQ[COUT];
#pragma unroll
  for (int o = 0; o < COUT; o++) { accS[o] = 0.f; accQ[o] = 0.f; }

  int l0 = R * tid;  // first output index; LIN % R == 0 so all R valid if l0 < LIN
  if (l0 < LIN) {
    const float* base = in + (long)n * sn + (long)b * sb;
    float y[COUT][R];
#pragma unroll
    for (int o = 0; o < COUT; o++)
#pragma unroll
      for (int r = 0; r < R; r++) y[o][r] = 0.f;

#pragma unroll
    for (int c = 0; c < CIN; c++) {
      // load aligned span [l0-4, l0+R+4) as (R+8)/4 float4s
      const float4* b4 = (const float4*)(base + (long)c * sc);
      float x[R + 8];
#pragma unroll
      for (int v = 0; v < (R + 8) / 4; v++) {
        int vi = l0 / 4 - 1 + v;
        float4 t = (vi >= 0 && vi < LIN / 4) ? b4[vi]
                                             : make_float4(0.f, 0.f, 0.f, 0.f);
        x[4 * v + 0] = t.x; x[4 * v + 1] = t.y;
        x[4 * v + 2] = t.z; x[4 * v + 3] = t.w;
      }
      // x[j] holds input element l0 - 4 + j; window for output r: [l0+r-3, l0+r+3]
#pragma unroll
      for (int k = 0; k < 7; k++) {
#pragma unroll
        for (int o = 0; o < COUT; o++) {
          float wv = w[(o * CIN + c) * 7 + k];  // uniform -> s_load
#pragma unroll
          for (int r = 0; r < R; r++)
            y[o][r] += wv * x[r + 1 + k];  // (l0+r-3+k) - (l0-4) = r+1+k
        }
      }
    }
#pragma unroll
    for (int o = 0; o < COUT; o++)
#pragma unroll
      for (int r = 0; r < R; r++) {
        accS[o] += y[o][r];
        accQ[o] += y[o][r] * y[o][r];
      }
  }

  __shared__ float s_part[2][NTH / 64][COUT];
  int lane = tid & 63, wv = tid >> 6;
#pragma unroll
  for (int o = 0; o < COUT; o++) {
    float v = accS[o], v2 = accQ[o];
#pragma unroll
    for (int off = 32; off > 0; off >>= 1) {
      v += __shfl_down(v, off, 64);
      v2 += __shfl_down(v2, off, 64);
    }
    if (lane == 0) { s_part[0][wv][o] = v; s_part[1][wv][o] = v2; }
  }
  __syncthreads();
  if (tid < COUT) {
    float s = 0.f, s2 = 0.f;
#pragma unroll
    for (int wvi = 0; wvi < NTH / 64; wvi++) {
      s += s_part[0][wvi][tid];
      s2 += s_part[1][wvi][tid];
    }
    atomicAdd(&stats[n * 64 + tid], s);
    atomicAdd(&stats[n * 64 + 32 + tid], s2);
  }
}

// ---------------------------------------------------------------------------
// Apply pass: conv again + BN(train stats) + ReLU + MaxPool(2) -> h
// grid: (ceil(LP/256), B, N), block: 256.  outh layout [n][b][COUT][LP]
// ---------------------------------------------------------------------------
template<int CIN, int COUT, int LIN>
__global__ __launch_bounds__(256) void conv_bn_pool(
    const float* __restrict__ in, long sn, long sb, long sc,
    const float* __restrict__ w,
    const float* __restrict__ gamma, const float* __restrict__ beta,
    const float* __restrict__ stats,
    float* __restrict__ outh) {
  const int LP = LIN / 2;
  __shared__ float s_in[CIN][2 * 256 + 8];
  __shared__ float s_scale[COUT], s_shift[COUT];
  int tid = threadIdx.x;
  int n = blockIdx.z, b = blockIdx.y;
  int p0 = blockIdx.x * 256;
  const float* base = in + (long)n * sn + (long)b * sb;
  if (tid < COUT) {
    float cnt = (float)BSZ * (float)LIN;
    float m = stats[n * 64 + tid] / cnt;
    float v = stats[n * 64 + 32 + tid] / cnt - m * m;
    float istd = 1.0f / sqrtf(v + BN_EPS);
    float scl = gamma[tid] * istd;
    s_scale[tid] = scl;
    s_shift[tid] = beta[tid] - m * scl;
  }
  int l0 = 2 * p0 - 3;
  for (int c = 0; c < CIN; c++)
    for (int i = tid; i < 2 * 256 + 7; i += 256) {
      int l = l0 + i;
      s_in[c][i] = (l >= 0 && l < LIN) ? base[(long)c * sc + l] : 0.f;
    }
  __syncthreads();
  int pl = p0 + tid;
  if (pl >= LP) return;
  float a0[COUT], a1[COUT];
#pragma unroll
  for (int o = 0; o < COUT; o++) { a0[o] = 0.f; a1[o] = 0.f; }
#pragma unroll
  for (int c = 0; c < CIN; c++) {
#pragma unroll
    for (int k = 0; k < 7; k++) {
      float x0 = s_in[c][2 * tid + k];
      float x1 = s_in[c][2 * tid + 1 + k];
#pragma unroll
      for (int o = 0; o < COUT; o++) {
        float wv = w[(o * CIN + c) * 7 + k];
        a0[o] += x0 * wv;
        a1[o] += x1 * wv;
      }
    }
  }
  long obase = ((long)n * BSZ + b) * COUT * (long)LP + pl;
#pragma unroll
  for (int o = 0; o < COUT; o++) {
    float r0 = a0[o] * s_scale[o] + s_shift[o];
    float r1 = a1[o] * s_scale[o] + s_shift[o];
    outh[obase + (long)o * LP] = fmaxf(fmaxf(r0, r1), 0.f);
  }
}

// ---------------------------------------------------------------------------
// Block 3 apply fused with AdaptiveAvgPool(1): writes feat[b][n][16] directly.
// grid: (1, B, N), block 256 (covers whole LP=250 row)
// ---------------------------------------------------------------------------
template<int CIN, int COUT, int LIN>
__global__ __launch_bounds__(256) void conv_bn_pool_feat(
    const float* __restrict__ in, long sn, long sb, long sc,
    const float* __restrict__ w,
    const float* __restrict__ gamma, const float* __restrict__ beta,
    const float* __restrict__ stats,
    float* __restrict__ feat) {
  const int LP = LIN / 2;
  __shared__ float s_in[CIN][2 * 256 + 8];
  __shared__ float s_scale[COUT], s_shift[COUT];
  __shared__ float s_part[4][COUT];
  int tid = threadIdx.x;
  int n = blockIdx.z, b = blockIdx.y;
  const float* base = in + (long)n * sn + (long)b * sb;
  if (tid < COUT) {
    float cnt = (float)BSZ * (float)LIN;
    float m = stats[n * 64 + tid] / cnt;
    float v = stats[n * 64 + 32 + tid] / cnt - m * m;
    float istd = 1.0f / sqrtf(v + BN_EPS);
    float scl = gamma[tid] * istd;
    s_scale[tid] = scl;
    s_shift[tid] = beta[tid] - m * scl;
  }
  for (int c = 0; c < CIN; c++)
    for (int i = tid; i < 2 * 256 + 7; i += 256) {
      int l = i - 3;
      s_in[c][i] = (l >= 0 && l < LIN) ? base[(long)c * sc + l] : 0.f;
    }
  __syncthreads();
  bool valid = (tid < LP);
  float a0[COUT], a1[COUT];
#pragma unroll
  for (int o = 0; o < COUT; o++) { a0[o] = 0.f; a1[o] = 0.f; }
#pragma unroll
  for (int c = 0; c < CIN; c++) {
#pragma unroll
    for (int k = 0; k < 7; k++) {
      float x0 = s_in[c][2 * tid + k];
      float x1 = s_in[c][2 * tid + 1 + k];
#pragma unroll
      for (int o = 0; o < COUT; o++) {
        float wv = w[(o * CIN + c) * 7 + k];
        a0[o] += x0 * wv;
        a1[o] += x1 * wv;
      }
    }
  }
  int wv2 = tid >> 6, lane = tid & 63;
#pragma unroll
  for (int o = 0; o < COUT; o++) {
    float r0 = a0[o] * s_scale[o] + s_shift[o];
    float r1 = a1[o] * s_scale[o] + s_shift[o];
    float h = valid ? fmaxf(fmaxf(r0, r1), 0.f) : 0.f;
#pragma unroll
    for (int off = 32; off > 0; off >>= 1) h += __shfl_down(h, off, 64);
    if (lane == 0) s_part[wv2][o] = h;
  }
  __syncthreads();
  if (tid < COUT) {
    float s = s_part[0][tid] + s_part[1][tid] + s_part[2][tid] + s_part[3][tid];
    feat[((long)b * NND + n) * COUT + tid] = s * (1.0f / (float)LP);
  }
}

// ---------------------------------------------------------------------------
// Graph tail: adjacency (top-4 incl self) + 3 GCN layers + node-mean + MLP head
// grid: (B), block: 256. One workgroup per batch element, all in LDS.
// ---------------------------------------------------------------------------
__global__ __launch_bounds__(256) void graph_head(
    const float* __restrict__ feat,
    const float* __restrict__ gw1, const float* __restrict__ gb1,
    const float* __restrict__ gw2, const float* __restrict__ gb2,
    const float* __restrict__ gw3, const float* __restrict__ gb3,
    const float* __restrict__ fw1, const float* __restrict__ fb1,
    const float* __restrict__ fw2, const float* __restrict__ fb2,
    float* __restrict__ out) {
  int b = blockIdx.x, tid = threadIdx.x;
  __shared__ float s_feat[NND][16];
  __shared__ float s_sq[NND];
  __shared__ float s_dist[NND][NND];
  __shared__ float s_adj[NND][NND];
  __shared__ float s_x[NND][128];
  __shared__ float s_t[NND][128];
  __shared__ float s_pool[128];
  __shared__ float s_h[64];
  for (int i = tid; i < NND * 16; i += 256) s_feat[i >> 4][i & 15] = feat[b * NND * 16 + i];
  __syncthreads();
  if (tid < NND) {
    float s = 0.f;
    for (int c = 0; c < 16; c++) s += s_feat[tid][c] * s_feat[tid][c];
    s_sq[tid] = s;
  }
  __syncthreads();
  for (int i = tid; i < NND * NND; i += 256) {
    int nn = i / NND, m = i % NND;
    float d = 0.f;
    for (int c = 0; c < 16; c++) d += s_feat[nn][c] * s_feat[m][c];
    s_dist[nn][m] = s_sq[nn] + s_sq[m] - 2.f * d;  // diagonal exactly 0
    s_adj[nn][m] = 0.f;
  }
  __syncthreads();
  if (tid < NND) {  // top-4 smallest per row, ties -> earliest index (matches top_k)
    unsigned used = 0;
    for (int j = 0; j < 4; j++) {
      float best = 3.4e38f; int bi = 0;
      for (int m = 0; m < NND; m++)
        if (!((used >> m) & 1u) && s_dist[tid][m] < best) { best = s_dist[tid][m]; bi = m; }
      used |= 1u << bi;
      s_adj[tid][bi] = 0.25f;
    }
  }
  __syncthreads();
  // ---- GCN layer 1: 16 -> 32 ----
  for (int i = tid; i < NND * 32; i += 256) {
    int nn = i / 32, f = i % 32;
    float a = 0.f;
    for (int c = 0; c < 16; c++) a += s_feat[nn][c] * gw1[c * 32 + f];
    s_t[nn][f] = a;
  }
  __syncthreads();
  for (int i = tid; i < NND * 32; i += 256) {
    int nn = i / 32, f = i % 32;
    float a = gb1[f];
    for (int m = 0; m < NND; m++) a += s_adj[nn][m] * s_t[m][f];
    s_x[nn][f] = fmaxf(a, 0.f);
  }
  __syncthreads();
  // ---- GCN layer 2: 32 -> 64 ----
  for (int i = tid; i < NND * 64; i += 256) {
    int nn = i / 64, f = i % 64;
    float a = 0.f;
    for (int c = 0; c < 32; c++) a += s_x[nn][c] * gw2[c * 64 + f];
    s_t[nn][f] = a;
  }
  __syncthreads();
  for (int i = tid; i < NND * 64; i += 256) {
    int nn = i / 64, f = i % 64;
    float a = gb2[f];
    for (int m = 0; m < NND; m++) a += s_adj[nn][m] * s_t[m][f];
    s_x[nn][f] = fmaxf(a, 0.f);
  }
  __syncthreads();
  // ---- GCN layer 3: 64 -> 128 ----
  for (int i = tid; i < NND * 128; i += 256) {
    int nn = i / 128, f = i % 128;
    float a = 0.f;
    for (int c = 0; c < 64; c++) a += s_x[nn][c] * gw3[c * 128 + f];
    s_t[nn][f] = a;
  }
  __syncthreads();
  for (int i = tid; i < NND * 128; i += 256) {
    int nn = i / 128, f = i % 128;
    float a = gb3[f];
    for (int m = 0; m < NND; m++) a += s_adj[nn][m] * s_t[m][f];
    s_x[nn][f] = fmaxf(a, 0.f);
  }
  __syncthreads();
  if (tid < 128) {
    float a = 0.f;
    for (int m = 0; m < NND; m++) a += s_x[m][tid];
    s_pool[tid] = a * (1.0f / (float)NND);
  }
  __syncthreads();
  if (tid < 64) {
    float a = fb1[tid];
    for (int c = 0; c < 128; c++) a += s_pool[c] * fw1[c * 64 + tid];
    s_h[tid] = a;
  }
  __syncthreads();
  if (tid < 4) {
    float a = fb2[tid];
    for (int c = 0; c < 64; c++) a += s_h[c] * fw2[c * 4 + tid];
    out[b * 4 + tid] = a;
  }
}

extern "C" void kernel_launch(void* const* d_in, const int* in_sizes, int n_in,
                              void* d_out, int out_size, void* d_ws, size_t ws_size,
                              hipStream_t stream) {
  (void)in_sizes; (void)n_in; (void)out_size; (void)ws_size;
  const float* x   = (const float*)d_in[0];
  const float* w1  = (const float*)d_in[1];
  const float* g1  = (const float*)d_in[2];
  const float* b1  = (const float*)d_in[3];
  const float* w2  = (const float*)d_in[4];
  const float* g2  = (const float*)d_in[5];
  const float* b2  = (const float*)d_in[6];
  const float* w3  = (const float*)d_in[7];
  const float* g3  = (const float*)d_in[8];
  const float* b3  = (const float*)d_in[9];
  const float* gw1 = (const float*)d_in[10];
  const float* gb1 = (const float*)d_in[11];
  const float* gw2 = (const float*)d_in[12];
  const float* gb2 = (const float*)d_in[13];
  const float* gw3 = (const float*)d_in[14];
  const float* gb3 = (const float*)d_in[15];
  const float* fw1 = (const float*)d_in[16];
  const float* fb1 = (const float*)d_in[17];
  const float* fw2 = (const float*)d_in[18];
  const float* fb2 = (const float*)d_in[19];

  float* ws = (float*)d_ws;
  const long H1 = (long)NND * BSZ * 4 * 1000;  // 22,528,000 floats
  const long H2 = (long)NND * BSZ * 8 * 500;   // 22,528,000 floats
  float* h1   = ws;
  float* h2   = h1 + H1;
  float* feat = h2 + H2;                        // B*N*16 = 90,112
  float* st1  = feat + (long)BSZ * NND * 16;    // 22*64 floats each, padded
  float* st2  = st1 + NND * 64;
  float* st3  = st2 + NND * 64;

  hipMemsetAsync(st1, 0, 3 * NND * 64 * sizeof(float), stream);

  // block 1: input x is (B, N, T): node stride T, batch stride N*T
  conv_stats_flat<1, 4, 2000, 8, 256><<<dim3(1, BSZ, NND), dim3(256), 0, stream>>>(
      x, 2000, (long)NND * 2000, 0, w1, st1);
  conv_bn_pool<1, 4, 2000><<<dim3(4, BSZ, NND), dim3(256), 0, stream>>>(
      x, 2000, (long)NND * 2000, 0, w1, g1, b1, st1, h1);
  // block 2: h1 layout [n][b][4][1000]
  conv_stats_flat<4, 8, 1000, 4, 256><<<dim3(1, BSZ, NND), dim3(256), 0, stream>>>(
      h1, (long)BSZ * 4000, 4000, 1000, w2, st2);
  conv_bn_pool<4, 8, 1000><<<dim3(2, BSZ, NND), dim3(256), 0, stream>>>(
      h1, (long)BSZ * 4000, 4000, 1000, w2, g2, b2, st2, h2);
  // block 3: h2 layout [n][b][8][500]; apply pass fused with avg-pool -> feat
  conv_stats_flat<8, 16, 500, 4, 128><<<dim3(1, BSZ, NND), dim3(128), 0, stream>>>(
      h2, (long)BSZ * 4000, 4000, 500, w3, st3);
  conv_bn_pool_feat<8, 16, 500><<<dim3(1, BSZ, NND), dim3(256), 0, stream>>>(
      h2, (long)BSZ * 4000, 4000, 500, w3, g3, b3, st3, feat);
  // graph tail
  graph_head<<<dim3(BSZ), dim3(256), 0, stream>>>(
      feat, gw1, gb1, gw2, gb2, gw3, gb3, fw1, fb1, fw2, fb2, (float*)d_out);
}

// Round 4
// 438.001 us; speedup vs baseline: 2.0296x; 1.0173x over previous
//
#include <hip/hip_runtime.h>

#define BSZ 256
#define NND 22
#define BN_EPS 1e-5f

// ---------------------------------------------------------------------------
// Stats pass (tiled, apply-structure): conv1d(k=7,pad=3), accumulate
// per-channel sum/sum^2 over the tile, block-reduce, write PRIVATE partial
// slot (no atomics). TILE=512 conv outputs per block, 2 per thread.
// partials layout: slot = ((n*NT + tile)*BSZ + b), V=2*COUT floats per slot
// grid: (NT, B, N), block: 256
// ---------------------------------------------------------------------------
template<int CIN, int COUT, int LIN, int NT>
__global__ __launch_bounds__(256) void conv_stats_tiled(
    const float* __restrict__ in, long sn, long sb, long sc,
    const float* __restrict__ w,
    float* __restrict__ part) {
  const int TILE = 512;
  __shared__ float s_in[CIN][TILE + 8];
  __shared__ float s_part[2][4][COUT];
  int tid = threadIdx.x;
  int n = blockIdx.z, b = blockIdx.y;
  int t0 = blockIdx.x * TILE;
  const float* base = in + (long)n * sn + (long)b * sb;
  for (int c = 0; c < CIN; c++)
    for (int i = tid; i < TILE + 6; i += 256) {
      int l = t0 + i - 3;
      s_in[c][i] = (l >= 0 && l < LIN) ? base[(long)c * sc + l] : 0.f;
    }
  __syncthreads();
  int p0 = t0 + 2 * tid;
  float a0[COUT], a1[COUT];
#pragma unroll
  for (int o = 0; o < COUT; o++) { a0[o] = 0.f; a1[o] = 0.f; }
#pragma unroll
  for (int c = 0; c < CIN; c++) {
#pragma unroll
    for (int k = 0; k < 7; k++) {
      float x0 = s_in[c][2 * tid + k];
      float x1 = s_in[c][2 * tid + 1 + k];
#pragma unroll
      for (int o = 0; o < COUT; o++) {
        float wv = w[(o * CIN + c) * 7 + k];  // uniform -> s_load
        a0[o] += x0 * wv;
        a1[o] += x1 * wv;
      }
    }
  }
  bool v0 = (p0 < LIN), v1 = (p0 + 1 < LIN);
  int lane = tid & 63, wv2 = tid >> 6;
#pragma unroll
  for (int o = 0; o < COUT; o++) {
    float y0 = v0 ? a0[o] : 0.f;
    float y1 = v1 ? a1[o] : 0.f;
    float s = y0 + y1;
    float q = y0 * y0 + y1 * y1;
#pragma unroll
    for (int off = 32; off > 0; off >>= 1) {
      s += __shfl_down(s, off, 64);
      q += __shfl_down(q, off, 64);
    }
    if (lane == 0) { s_part[0][wv2][o] = s; s_part[1][wv2][o] = q; }
  }
  __syncthreads();
  long slot = ((long)n * NT + blockIdx.x) * BSZ + b;
  if (tid < COUT) {
    float s = s_part[0][0][tid] + s_part[0][1][tid] + s_part[0][2][tid] + s_part[0][3][tid];
    float q = s_part[1][0][tid] + s_part[1][1][tid] + s_part[1][2][tid] + s_part[1][3][tid];
    part[slot * (2 * COUT) + tid] = s;
    part[slot * (2 * COUT) + COUT + tid] = q;
  }
}

// ---------------------------------------------------------------------------
// Reduce partials -> BN scale/shift per (node, channel).
// scs layout: scs[n*64 + o] = scale, scs[n*64 + 32 + o] = shift
// grid: (NND), block: 256
// ---------------------------------------------------------------------------
template<int C, int NSLOT, int LIN>
__global__ __launch_bounds__(256) void stats_reduce(
    const float* __restrict__ part,
    const float* __restrict__ gamma, const float* __restrict__ beta,
    float* __restrict__ scs) {
  const int V = 2 * C;
  const int GRP = 256 / V;
  int n = blockIdx.x, tid = threadIdx.x;
  int j = tid % V, g = tid / V;
  const float* p = part + (long)n * NSLOT * V;
  float s = 0.f;
  for (int sl = g; sl < NSLOT; sl += GRP) s += p[(long)sl * V + j];
  __shared__ float red[V][GRP];
  __shared__ float tot[V];
  red[j][g] = s;
  __syncthreads();
  if (tid < V) {
    float t = 0.f;
#pragma unroll
    for (int gg = 0; gg < GRP; gg++) t += red[tid][gg];
    tot[tid] = t;
  }
  __syncthreads();
  if (tid < C) {
    float cnt = (float)BSZ * (float)LIN;
    float m = tot[tid] / cnt;
    float var = tot[C + tid] / cnt - m * m;
    float istd = 1.0f / sqrtf(var + BN_EPS);
    float scl = gamma[tid] * istd;
    scs[n * 64 + tid] = scl;
    scs[n * 64 + 32 + tid] = beta[tid] - m * scl;
  }
}

// ---------------------------------------------------------------------------
// Apply pass: conv + BN(scale/shift) + ReLU + MaxPool(2) -> h
// grid: (ceil(LP/256), B, N), block: 256.  outh layout [n][b][COUT][LP]
// ---------------------------------------------------------------------------
template<int CIN, int COUT, int LIN>
__global__ __launch_bounds__(256) void conv_bn_pool(
    const float* __restrict__ in, long sn, long sb, long sc,
    const float* __restrict__ w,
    const float* __restrict__ scs,
    float* __restrict__ outh) {
  const int LP = LIN / 2;
  __shared__ float s_in[CIN][2 * 256 + 8];
  __shared__ float s_scale[COUT], s_shift[COUT];
  int tid = threadIdx.x;
  int n = blockIdx.z, b = blockIdx.y;
  int p0 = blockIdx.x * 256;
  const float* base = in + (long)n * sn + (long)b * sb;
  if (tid < COUT) {
    s_scale[tid] = scs[n * 64 + tid];
    s_shift[tid] = scs[n * 64 + 32 + tid];
  }
  int l0 = 2 * p0 - 3;
  for (int c = 0; c < CIN; c++)
    for (int i = tid; i < 2 * 256 + 7; i += 256) {
      int l = l0 + i;
      s_in[c][i] = (l >= 0 && l < LIN) ? base[(long)c * sc + l] : 0.f;
    }
  __syncthreads();
  int pl = p0 + tid;
  if (pl >= LP) return;
  float a0[COUT], a1[COUT];
#pragma unroll
  for (int o = 0; o < COUT; o++) { a0[o] = 0.f; a1[o] = 0.f; }
#pragma unroll
  for (int c = 0; c < CIN; c++) {
#pragma unroll
    for (int k = 0; k < 7; k++) {
      float x0 = s_in[c][2 * tid + k];
      float x1 = s_in[c][2 * tid + 1 + k];
#pragma unroll
      for (int o = 0; o < COUT; o++) {
        float wv = w[(o * CIN + c) * 7 + k];
        a0[o] += x0 * wv;
        a1[o] += x1 * wv;
      }
    }
  }
  long obase = ((long)n * BSZ + b) * COUT * (long)LP + pl;
#pragma unroll
  for (int o = 0; o < COUT; o++) {
    float r0 = a0[o] * s_scale[o] + s_shift[o];
    float r1 = a1[o] * s_scale[o] + s_shift[o];
    outh[obase + (long)o * LP] = fmaxf(fmaxf(r0, r1), 0.f);
  }
}

// ---------------------------------------------------------------------------
// Block 3 apply fused with AdaptiveAvgPool(1): writes feat[b][n][16] directly.
// grid: (1, B, N), block 256 (covers whole LP=250 row)
// ---------------------------------------------------------------------------
template<int CIN, int COUT, int LIN>
__global__ __launch_bounds__(256) void conv_bn_pool_feat(
    const float* __restrict__ in, long sn, long sb, long sc,
    const float* __restrict__ w,
    const float* __restrict__ scs,
    float* __restrict__ feat) {
  const int LP = LIN / 2;
  __shared__ float s_in[CIN][2 * 256 + 8];
  __shared__ float s_scale[COUT], s_shift[COUT];
  __shared__ float s_part[4][COUT];
  int tid = threadIdx.x;
  int n = blockIdx.z, b = blockIdx.y;
  const float* base = in + (long)n * sn + (long)b * sb;
  if (tid < COUT) {
    s_scale[tid] = scs[n * 64 + tid];
    s_shift[tid] = scs[n * 64 + 32 + tid];
  }
  for (int c = 0; c < CIN; c++)
    for (int i = tid; i < 2 * 256 + 7; i += 256) {
      int l = i - 3;
      s_in[c][i] = (l >= 0 && l < LIN) ? base[(long)c * sc + l] : 0.f;
    }
  __syncthreads();
  bool valid = (tid < LP);
  float a0[COUT], a1[COUT];
#pragma unroll
  for (int o = 0; o < COUT; o++) { a0[o] = 0.f; a1[o] = 0.f; }
#pragma unroll
  for (int c = 0; c < CIN; c++) {
#pragma unroll
    for (int k = 0; k < 7; k++) {
      float x0 = s_in[c][2 * tid + k];
      float x1 = s_in[c][2 * tid + 1 + k];
#pragma unroll
      for (int o = 0; o < COUT; o++) {
        float wv = w[(o * CIN + c) * 7 + k];
        a0[o] += x0 * wv;
        a1[o] += x1 * wv;
      }
    }
  }
  int wv2 = tid >> 6, lane = tid & 63;
#pragma unroll
  for (int o = 0; o < COUT; o++) {
    float r0 = a0[o] * s_scale[o] + s_shift[o];
    float r1 = a1[o] * s_scale[o] + s_shift[o];
    float h = valid ? fmaxf(fmaxf(r0, r1), 0.f) : 0.f;
#pragma unroll
    for (int off = 32; off > 0; off >>= 1) h += __shfl_down(h, off, 64);
    if (lane == 0) s_part[wv2][o] = h;
  }
  __syncthreads();
  if (tid < COUT) {
    float s = s_part[0][tid] + s_part[1][tid] + s_part[2][tid] + s_part[3][tid];
    feat[((long)b * NND + n) * COUT + tid] = s * (1.0f / (float)LP);
  }
}

// ---------------------------------------------------------------------------
// Graph tail: adjacency (top-4 incl self) + 3 GCN layers + node-mean + MLP head
// grid: (B), block: 256. One workgroup per batch element, all in LDS.
// ---------------------------------------------------------------------------
__global__ __launch_bounds__(256) void graph_head(
    const float* __restrict__ feat,
    const float* __restrict__ gw1, const float* __restrict__ gb1,
    const float* __restrict__ gw2, const float* __restrict__ gb2,
    const float* __restrict__ gw3, const float* __restrict__ gb3,
    const float* __restrict__ fw1, const float* __restrict__ fb1,
    const float* __restrict__ fw2, const float* __restrict__ fb2,
    float* __restrict__ out) {
  int b = blockIdx.x, tid = threadIdx.x;
  __shared__ float s_feat[NND][16];
  __shared__ float s_sq[NND];
  __shared__ float s_dist[NND][NND];
  __shared__ float s_adj[NND][NND];
  __shared__ float s_x[NND][128];
  __shared__ float s_t[NND][128];
  __shared__ float s_pool[128];
  __shared__ float s_h[64];
  for (int i = tid; i < NND * 16; i += 256) s_feat[i >> 4][i & 15] = feat[b * NND * 16 + i];
  __syncthreads();
  if (tid < NND) {
    float s = 0.f;
    for (int c = 0; c < 16; c++) s += s_feat[tid][c] * s_feat[tid][c];
    s_sq[tid] = s;
  }
  __syncthreads();
  for (int i = tid; i < NND * NND; i += 256) {
    int nn = i / NND, m = i % NND;
    float d = 0.f;
    for (int c = 0; c < 16; c++) d += s_feat[nn][c] * s_feat[m][c];
    s_dist[nn][m] = s_sq[nn] + s_sq[m] - 2.f * d;  // diagonal exactly 0
    s_adj[nn][m] = 0.f;
  }
  __syncthreads();
  if (tid < NND) {  // top-4 smallest per row, ties -> earliest index (matches top_k)
    unsigned used = 0;
    for (int j = 0; j < 4; j++) {
      float best = 3.4e38f; int bi = 0;
      for (int m = 0; m < NND; m++)
        if (!((used >> m) & 1u) && s_dist[tid][m] < best) { best = s_dist[tid][m]; bi = m; }
      used |= 1u << bi;
      s_adj[tid][bi] = 0.25f;
    }
  }
  __syncthreads();
  // ---- GCN layer 1: 16 -> 32 ----
  for (int i = tid; i < NND * 32; i += 256) {
    int nn = i / 32, f = i % 32;
    float a = 0.f;
    for (int c = 0; c < 16; c++) a += s_feat[nn][c] * gw1[c * 32 + f];
    s_t[nn][f] = a;
  }
  __syncthreads();
  for (int i = tid; i < NND * 32; i += 256) {
    int nn = i / 32, f = i % 32;
    float a = gb1[f];
    for (int m = 0; m < NND; m++) a += s_adj[nn][m] * s_t[m][f];
    s_x[nn][f] = fmaxf(a, 0.f);
  }
  __syncthreads();
  // ---- GCN layer 2: 32 -> 64 ----
  for (int i = tid; i < NND * 64; i += 256) {
    int nn = i / 64, f = i % 64;
    float a = 0.f;
    for (int c = 0; c < 32; c++) a += s_x[nn][c] * gw2[c * 64 + f];
    s_t[nn][f] = a;
  }
  __syncthreads();
  for (int i = tid; i < NND * 64; i += 256) {
    int nn = i / 64, f = i % 64;
    float a = gb2[f];
    for (int m = 0; m < NND; m++) a += s_adj[nn][m] * s_t[m][f];
    s_x[nn][f] = fmaxf(a, 0.f);
  }
  __syncthreads();
  // ---- GCN layer 3: 64 -> 128 ----
  for (int i = tid; i < NND * 128; i += 256) {
    int nn = i / 128, f = i % 128;
    float a = 0.f;
    for (int c = 0; c < 64; c++) a += s_x[nn][c] * gw3[c * 128 + f];
    s_t[nn][f] = a;
  }
  __syncthreads();
  for (int i = tid; i < NND * 128; i += 256) {
    int nn = i / 128, f = i % 128;
    float a = gb3[f];
    for (int m = 0; m < NND; m++) a += s_adj[nn][m] * s_t[m][f];
    s_x[nn][f] = fmaxf(a, 0.f);
  }
  __syncthreads();
  if (tid < 128) {
    float a = 0.f;
    for (int m = 0; m < NND; m++) a += s_x[m][tid];
    s_pool[tid] = a * (1.0f / (float)NND);
  }
  __syncthreads();
  if (tid < 64) {
    float a = fb1[tid];
    for (int c = 0; c < 128; c++) a += s_pool[c] * fw1[c * 64 + tid];
    s_h[tid] = a;
  }
  __syncthreads();
  if (tid < 4) {
    float a = fb2[tid];
    for (int c = 0; c < 64; c++) a += s_h[c] * fw2[c * 4 + tid];
    out[b * 4 + tid] = a;
  }
}

extern "C" void kernel_launch(void* const* d_in, const int* in_sizes, int n_in,
                              void* d_out, int out_size, void* d_ws, size_t ws_size,
                              hipStream_t stream) {
  (void)in_sizes; (void)n_in; (void)out_size; (void)ws_size;
  const float* x   = (const float*)d_in[0];
  const float* w1  = (const float*)d_in[1];
  const float* g1  = (const float*)d_in[2];
  const float* b1  = (const float*)d_in[3];
  const float* w2  = (const float*)d_in[4];
  const float* g2  = (const float*)d_in[5];
  const float* b2  = (const float*)d_in[6];
  const float* w3  = (const float*)d_in[7];
  const float* g3  = (const float*)d_in[8];
  const float* b3  = (const float*)d_in[9];
  const float* gw1 = (const float*)d_in[10];
  const float* gb1 = (const float*)d_in[11];
  const float* gw2 = (const float*)d_in[12];
  const float* gb2 = (const float*)d_in[13];
  const float* gw3 = (const float*)d_in[14];
  const float* gb3 = (const float*)d_in[15];
  const float* fw1 = (const float*)d_in[16];
  const float* fb1 = (const float*)d_in[17];
  const float* fw2 = (const float*)d_in[18];
  const float* fb2 = (const float*)d_in[19];

  float* ws = (float*)d_ws;
  const long H1 = (long)NND * BSZ * 4 * 1000;  // 22,528,000 floats
  const long H2 = (long)NND * BSZ * 8 * 500;   // 22,528,000 floats
  float* h1   = ws;
  float* h2   = h1 + H1;
  float* feat = h2 + H2;                        // B*N*16 = 90,112
  float* scs1 = feat + (long)BSZ * NND * 16;    // scale/shift, 22*64 each
  float* scs2 = scs1 + NND * 64;
  float* scs3 = scs2 + NND * 64;
  float* p1   = scs3 + NND * 64;                // partials
  float* p2   = p1 + (long)NND * 4 * BSZ * 8;   // 22*4*256 slots * 8
  float* p3   = p2 + (long)NND * 2 * BSZ * 16;  // 22*2*256 slots * 16
  // p3: 22*1*256 slots * 32

  // block 1: input x is (B, N, T): node stride T, batch stride N*T
  conv_stats_tiled<1, 4, 2000, 4><<<dim3(4, BSZ, NND), dim3(256), 0, stream>>>(
      x, 2000, (long)NND * 2000, 0, w1, p1);
  stats_reduce<4, 4 * BSZ, 2000><<<dim3(NND), dim3(256), 0, stream>>>(p1, g1, b1, scs1);
  conv_bn_pool<1, 4, 2000><<<dim3(4, BSZ, NND), dim3(256), 0, stream>>>(
      x, 2000, (long)NND * 2000, 0, w1, scs1, h1);
  // block 2: h1 layout [n][b][4][1000]
  conv_stats_tiled<4, 8, 1000, 2><<<dim3(2, BSZ, NND), dim3(256), 0, stream>>>(
      h1, (long)BSZ * 4000, 4000, 1000, w2, p2);
  stats_reduce<8, 2 * BSZ, 1000><<<dim3(NND), dim3(256), 0, stream>>>(p2, g2, b2, scs2);
  conv_bn_pool<4, 8, 1000><<<dim3(2, BSZ, NND), dim3(256), 0, stream>>>(
      h1, (long)BSZ * 4000, 4000, 1000, w2, scs2, h2);
  // block 3: h2 layout [n][b][8][500]; apply pass fused with avg-pool -> feat
  conv_stats_tiled<8, 16, 500, 1><<<dim3(1, BSZ, NND), dim3(256), 0, stream>>>(
      h2, (long)BSZ * 4000, 4000, 500, w3, p3);
  stats_reduce<16, 1 * BSZ, 500><<<dim3(NND), dim3(256), 0, stream>>>(p3, g3, b3, scs3);
  conv_bn_pool_feat<8, 16, 500><<<dim3(1, BSZ, NND), dim3(256), 0, stream>>>(
      h2, (long)BSZ * 4000, 4000, 500, w3, scs3, feat);
  // graph tail
  graph_head<<<dim3(BSZ), dim3(256), 0, stream>>>(
      feat, gw1, gb1, gw2, gb2, gw3, gb3, fw1, fb1, fw2, fb2, (float*)d_out);
}